// Round 4
// baseline (433.617 us; speedup 1.0000x reference)
//
#include <hip/hip_runtime.h>
#include <stdint.h>

#define N_FEATS 131072
#define IN_SZ   256
#define HID     1024
#define OUT_SZ  256
#define NE      16

typedef __attribute__((ext_vector_type(8))) short short8;
typedef __attribute__((ext_vector_type(4))) float floatx4;

__device__ inline unsigned short f32_bf16(float f) {
    unsigned int u = __builtin_bit_cast(unsigned int, f);
    u += 0x7FFFu + ((u >> 16) & 1u);   // round-to-nearest-even
    return (unsigned short)(u >> 16);
}

// ---------------- bucketing ----------------
__global__ void k_hist(const int* __restrict__ ids, int* __restrict__ counts) {
    __shared__ int lc[NE];
    int t = threadIdx.x;
    if (t < NE) lc[t] = 0;
    __syncthreads();
    for (int i = blockIdx.x * blockDim.x + t; i < N_FEATS; i += gridDim.x * blockDim.x)
        atomicAdd(&lc[ids[i]], 1);
    __syncthreads();
    if (t < NE) atomicAdd(&counts[t], lc[t]);
}

__global__ void k_scan(const int* __restrict__ counts, int* __restrict__ offsets,
                       int* __restrict__ tilep) {
    if (threadIdx.x == 0 && blockIdx.x == 0) {
        int o = 0, tp = 0;
        for (int e = 0; e < NE; e++) {
            offsets[e] = o; tilep[e] = tp;
            o += counts[e];
            tp += (counts[e] + 63) >> 6;
        }
        offsets[NE] = o; tilep[NE] = tp;
    }
}

// Per-block aggregated scatter.
#define SC_CHUNK 512
__global__ void k_scatter(const int* __restrict__ ids, const int* __restrict__ offsets,
                          int* __restrict__ cursors, int* __restrict__ bucket) {
    __shared__ int lcnt[NE];
    __shared__ int lbase[NE];
    int t = threadIdx.x;
    int base = blockIdx.x * SC_CHUNK;
    if (t < NE) lcnt[t] = 0;
    __syncthreads();
    int i0 = base + t, i1 = base + 256 + t;
    int e0 = ids[i0], e1 = ids[i1];
    int p0 = atomicAdd(&lcnt[e0], 1);
    int p1 = atomicAdd(&lcnt[e1], 1);
    __syncthreads();
    if (t < NE) lbase[t] = atomicAdd(&cursors[t], lcnt[t]);
    __syncthreads();
    bucket[offsets[e0] + lbase[e0] + p0] = i0;
    bucket[offsets[e1] + lbase[e1] + p1] = i1;
}

// ---------------- weight pack: f32 [E][K][N] -> bf16 MFMA-B-frag order ----------------
// dst layout: [E][N/16][K/32][lane(64)][8], lane = quad*16 + l15 holds
// B[k = ks*32 + quad*8 + j][n = n16*16 + l15].
// grid: (K/256, N/16, E), block 256. Source reads non-temporal (read-once).
__global__ void k_pack(const float* __restrict__ src, unsigned short* __restrict__ dst,
                       int K, int N) {
    __shared__ float ld[256][17];
    int kc = blockIdx.x, n16 = blockIdx.y, e = blockIdx.z;
    int t = threadIdx.x;
    const float* s = src + ((size_t)e * K + kc * 256) * N + n16 * 16;
    int tn = t & 15, tk = t >> 4;
#pragma unroll
    for (int p = 0; p < 16; p++) {
        int k = p * 16 + tk;
        ld[k][tn] = __builtin_nontemporal_load(&s[(size_t)k * N + tn]);
    }
    __syncthreads();
    unsigned short* d = dst + (((size_t)e * (N / 16) + n16) * (K / 32) + kc * 8) * 512;
#pragma unroll
    for (int u = 0; u < 2; u++) {
        int o = t * 16 + u * 8;           // short8 element offset
        int ks = o >> 9;                  // local ks 0..7
        int lane = (o >> 3) & 63;
        int kbase = ks * 32 + ((lane >> 4) & 3) * 8;
        int n = lane & 15;
        short8 v;
#pragma unroll
        for (int j = 0; j < 8; j++) v[j] = (short)f32_bf16(ld[kbase + j][n]);
        *(short8*)(d + o) = v;
    }
}

// ---------------- fused grouped 2-layer MLP ----------------
// Round-4 change: VGPR_Count=128 proved the pre-RA scheduler sank the hoisted
// weight loads back to their uses (only ~3 frags in flight -> ~11 exposed L2
// round-trips per hc). sched_barrier(0) after each load cluster pins the
// 16-deep load batches; expected VGPR ~200-230, 2 waves/SIMD, no spill.
#define SLOTS_PER_XCD 288
__global__ __launch_bounds__(256, 2) void k_mlp(
    const float* __restrict__ x, const float* __restrict__ b1, const float* __restrict__ b2,
    const unsigned short* __restrict__ w1fr, const unsigned short* __restrict__ w2fr,
    const int* __restrict__ bucket, const int* __restrict__ offsets,
    const int* __restrict__ tilep, float* __restrict__ out)
{
    __shared__ __align__(16) unsigned short xs[4 * 8 * 64 * 8];  // 32 KB
    __shared__ __align__(16) unsigned short hs[4 * 4 * 64 * 8];  // 16 KB
    __shared__ int rows_s[64];

    int slots = gridDim.x >> 3;
    int xcd  = blockIdx.x & 7;
    int slot = blockIdx.x >> 3;
    int eA = xcd, eB = xcd + 8;
    int T0 = tilep[eA + 1] - tilep[eA];
    int T1 = tilep[eB + 1] - tilep[eB];
    int total = T0 + T1;

    int t = threadIdx.x;
    int lane = t & 63, w = t >> 6;
    int l15 = lane & 15, quad = lane >> 4;

    for (int s = slot; s < total; s += slots) {
        int e    = (s < T0) ? eA : eB;
        int tile = (s < T0) ? s  : s - T0;
        int off  = offsets[e];
        int cnt  = offsets[e + 1] - off;
        int valid = min(64, cnt - tile * 64);

        if (t < 64)
            rows_s[t] = bucket[off + tile * 64 + min(t, valid - 1)];
        __syncthreads();

        // stage x tile f32->bf16 into swizzled A-frag order (nt: read-once stream)
#pragma unroll
        for (int p = 0; p < 8; p++) {
            int item = p * 256 + t;
            int c8 = item & 31, r = item >> 5;
            const float* xr = x + (size_t)rows_s[r] * IN_SZ + c8 * 8;
            floatx4 v0 = __builtin_nontemporal_load((const floatx4*)xr);
            floatx4 v1 = __builtin_nontemporal_load((const floatx4*)(xr + 4));
            int ks = c8 >> 2, q = c8 & 3;
            short8 o;
            o[0] = (short)f32_bf16(v0.x); o[1] = (short)f32_bf16(v0.y);
            o[2] = (short)f32_bf16(v0.z); o[3] = (short)f32_bf16(v0.w);
            o[4] = (short)f32_bf16(v1.x); o[5] = (short)f32_bf16(v1.y);
            o[6] = (short)f32_bf16(v1.z); o[7] = (short)f32_bf16(v1.w);
            *(short8*)&xs[(((r >> 4) * 8 + ks) * 64 + q * 16 + ((r & 15) ^ ks)) * 8] = o;
        }
        __syncthreads();

        floatx4 acc2[4][4] = {};  // [m-tile][n-tile], out cols w*64 + j*16 + l15
        const unsigned short* w1e = w1fr + (size_t)e * 64 * 4096;        // 64 n16 x (8 ks x 512)
        const unsigned short* w2e = w2fr + (size_t)e * 16 * 32 * 512;    // 16 n16 x (32 kst x 512)

        for (int hc = 0; hc < 8; hc++) {
            // ---- layer 1: wave w computes hidden cols hc*128 + w*32 + j1*16 + l15
            int n16_0 = hc * 8 + w * 2;
            const unsigned short* bb0 = w1e + (size_t)n16_0 * 4096 + lane * 8;

            // hoist: all 16 layer-1 weight frags in flight at once
            short8 bw1[2][8];
#pragma unroll
            for (int ks = 0; ks < 8; ks++) {
                bw1[0][ks] = *(const short8*)(bb0 + ks * 512);
                bw1[1][ks] = *(const short8*)(bb0 + 4096 + ks * 512);
            }
            // pin the cluster: pressure-aware scheduler must not sink these
            __builtin_amdgcn_sched_barrier(0);

            floatx4 acc1[2][4] = {};
#pragma unroll
            for (int ks = 0; ks < 8; ks++) {
                int xoff = (ks * 64 + quad * 16 + (l15 ^ ks)) * 8;
#pragma unroll
                for (int i = 0; i < 4; i++) {
                    short8 af = *(const short8*)&xs[i * 4096 + xoff];
                    acc1[0][i] = __builtin_amdgcn_mfma_f32_16x16x32_bf16(af, bw1[0][ks], acc1[0][i], 0, 0, 0);
                    acc1[1][i] = __builtin_amdgcn_mfma_f32_16x16x32_bf16(af, bw1[1][ks], acc1[1][i], 0, 0, 0);
                }
            }
            __builtin_amdgcn_sched_barrier(0);

            // issue ALL layer-2 weight frags now: latency hides under the
            // bias/relu VALU work + hs writes + barrier below
            short8 bw2[4][4];
#pragma unroll
            for (int j = 0; j < 4; j++)
#pragma unroll
                for (int ks2 = 0; ks2 < 4; ks2++)
                    bw2[j][ks2] = *(const short8*)(w2e + (((size_t)(w * 4 + j) * 32) + hc * 4 + ks2) * 512 + lane * 8);
            // pin: keep 16 loads issued here, not sunk into the L2 MFMA loop
            __builtin_amdgcn_sched_barrier(0);

            // bias + relu; C-layout -> hs A-frag order
            int n1base = hc * 128 + w * 32;
#pragma unroll
            for (int j1 = 0; j1 < 2; j1++) {
                float b1v = b1[e * HID + n1base + j1 * 16 + l15];
                int q2 = j1 * 2 + (l15 >> 3);
                int j2 = l15 & 7;
#pragma unroll
                for (int i = 0; i < 4; i++) {
#pragma unroll
                    for (int r = 0; r < 4; r++) {
                        float v = acc1[j1][i][r] + b1v;
                        v = v > 0.f ? v : 0.f;
                        int m15 = quad * 4 + r;
                        hs[((i * 4 + w) * 64 + q2 * 16 + (m15 ^ q2)) * 8 + j2] = f32_bf16(v);
                    }
                }
            }
            __syncthreads();
            // ---- layer 2: acc2 += h_chunk @ W2 chunk
#pragma unroll
            for (int ks2 = 0; ks2 < 4; ks2++) {
                int hoff = (ks2 * 64 + quad * 16 + (l15 ^ quad)) * 8;
                short8 af[4];
#pragma unroll
                for (int i = 0; i < 4; i++)
                    af[i] = *(const short8*)&hs[i * 2048 + hoff];
#pragma unroll
                for (int j = 0; j < 4; j++) {
#pragma unroll
                    for (int i = 0; i < 4; i++)
                        acc2[i][j] = __builtin_amdgcn_mfma_f32_16x16x32_bf16(af[i], bw2[j][ks2], acc2[i][j], 0, 0, 0);
                }
            }
            __syncthreads();
        }

        // epilogue: + b2, scatter rows back (nt: write-once stream)
#pragma unroll
        for (int j = 0; j < 4; j++) {
            int col = w * 64 + j * 16 + l15;
            float b2v = b2[e * OUT_SZ + col];
#pragma unroll
            for (int i = 0; i < 4; i++) {
#pragma unroll
                for (int r = 0; r < 4; r++) {
                    int rt = 16 * i + quad * 4 + r;
                    if (rt < valid)
                        __builtin_nontemporal_store(acc2[i][j][r] + b2v,
                                                    &out[(size_t)rows_s[rt] * OUT_SZ + col]);
                }
            }
        }
        // protect rows_s / xs before the next grid-stride iteration overwrites them
        __syncthreads();
    }
}

extern "C" void kernel_launch(void* const* d_in, const int* in_sizes, int n_in,
                              void* d_out, int out_size, void* d_ws, size_t ws_size,
                              hipStream_t stream) {
    const float* x  = (const float*)d_in[0];
    const float* W1 = (const float*)d_in[1];
    const float* b1 = (const float*)d_in[2];
    const float* W2 = (const float*)d_in[3];
    const float* b2 = (const float*)d_in[4];
    const int*  ids = (const int*)d_in[5];
    float* out = (float*)d_out;

    char* ws = (char*)d_ws;
    int* counts  = (int*)(ws);          // 16
    int* cursors = (int*)(ws + 64);     // 16
    int* offsets = (int*)(ws + 128);    // 17
    int* tilep   = (int*)(ws + 256);    // 17
    int* bucket  = (int*)(ws + 1024);   // 131072 ints
    unsigned short* w1fr = (unsigned short*)(ws + (1 << 20));           // 8.39 MB
    unsigned short* w2fr = w1fr + (size_t)NE * HID * IN_SZ;             // 8.39 MB

    (void)hipMemsetAsync(ws, 0, 512, stream);
    hipLaunchKernelGGL(k_hist,    dim3(256), dim3(256), 0, stream, ids, counts);
    hipLaunchKernelGGL(k_scan,    dim3(1),   dim3(1),   0, stream, counts, offsets, tilep);
    hipLaunchKernelGGL(k_scatter, dim3(N_FEATS / SC_CHUNK), dim3(256), 0, stream,
                       ids, offsets, cursors, bucket);
    // W1: [16][256][1024] -> frag order; W2: [16][1024][256] -> frag order
    hipLaunchKernelGGL(k_pack, dim3(IN_SZ / 256, HID / 16, NE), dim3(256), 0, stream,
                       W1, w1fr, IN_SZ, HID);
    hipLaunchKernelGGL(k_pack, dim3(HID / 256, OUT_SZ / 16, NE), dim3(256), 0, stream,
                       W2, w2fr, HID, OUT_SZ);
    hipLaunchKernelGGL(k_mlp, dim3(8 * SLOTS_PER_XCD), dim3(256), 0, stream,
                       x, b1, b2, w1fr, w2fr, bucket, offsets, tilep, out);
}

// Round 5
// 429.016 us; speedup vs baseline: 1.0107x; 1.0107x over previous
//
#include <hip/hip_runtime.h>
#include <stdint.h>

#define N_FEATS 131072
#define IN_SZ   256
#define HID     1024
#define OUT_SZ  256
#define NE      16

typedef __attribute__((ext_vector_type(8))) short short8;
typedef __attribute__((ext_vector_type(4))) float floatx4;

__device__ inline unsigned short f32_bf16(float f) {
    unsigned int u = __builtin_bit_cast(unsigned int, f);
    u += 0x7FFFu + ((u >> 16) & 1u);   // round-to-nearest-even
    return (unsigned short)(u >> 16);
}

// ---------------- bucketing ----------------
__global__ void k_hist(const int* __restrict__ ids, int* __restrict__ counts) {
    __shared__ int lc[NE];
    int t = threadIdx.x;
    if (t < NE) lc[t] = 0;
    __syncthreads();
    for (int i = blockIdx.x * blockDim.x + t; i < N_FEATS; i += gridDim.x * blockDim.x)
        atomicAdd(&lc[ids[i]], 1);
    __syncthreads();
    if (t < NE) atomicAdd(&counts[t], lc[t]);
}

__global__ void k_scan(const int* __restrict__ counts, int* __restrict__ offsets,
                       int* __restrict__ tilep) {
    if (threadIdx.x == 0 && blockIdx.x == 0) {
        int o = 0, tp = 0;
        for (int e = 0; e < NE; e++) {
            offsets[e] = o; tilep[e] = tp;
            o += counts[e];
            tp += (counts[e] + 63) >> 6;
        }
        offsets[NE] = o; tilep[NE] = tp;
    }
}

// Per-block aggregated scatter.
#define SC_CHUNK 512
__global__ void k_scatter(const int* __restrict__ ids, const int* __restrict__ offsets,
                          int* __restrict__ cursors, int* __restrict__ bucket) {
    __shared__ int lcnt[NE];
    __shared__ int lbase[NE];
    int t = threadIdx.x;
    int base = blockIdx.x * SC_CHUNK;
    if (t < NE) lcnt[t] = 0;
    __syncthreads();
    int i0 = base + t, i1 = base + 256 + t;
    int e0 = ids[i0], e1 = ids[i1];
    int p0 = atomicAdd(&lcnt[e0], 1);
    int p1 = atomicAdd(&lcnt[e1], 1);
    __syncthreads();
    if (t < NE) lbase[t] = atomicAdd(&cursors[t], lcnt[t]);
    __syncthreads();
    bucket[offsets[e0] + lbase[e0] + p0] = i0;
    bucket[offsets[e1] + lbase[e1] + p1] = i1;
}

// ---------------- weight pack: f32 [E][K][N] -> bf16 MFMA-B-frag order ----------------
// dst layout: [E][N/16][K/32][lane(64)][8], lane = quad*16 + l15 holds
// B[k = ks*32 + quad*8 + j][n = n16*16 + l15].
// grid: (K/256, N/16, E), block 256. Source reads non-temporal (read-once).
__global__ void k_pack(const float* __restrict__ src, unsigned short* __restrict__ dst,
                       int K, int N) {
    __shared__ float ld[256][17];
    int kc = blockIdx.x, n16 = blockIdx.y, e = blockIdx.z;
    int t = threadIdx.x;
    const float* s = src + ((size_t)e * K + kc * 256) * N + n16 * 16;
    int tn = t & 15, tk = t >> 4;
#pragma unroll
    for (int p = 0; p < 16; p++) {
        int k = p * 16 + tk;
        ld[k][tn] = __builtin_nontemporal_load(&s[(size_t)k * N + tn]);
    }
    __syncthreads();
    unsigned short* d = dst + (((size_t)e * (N / 16) + n16) * (K / 32) + kc * 8) * 512;
#pragma unroll
    for (int u = 0; u < 2; u++) {
        int o = t * 16 + u * 8;           // short8 element offset
        int ks = o >> 9;                  // local ks 0..7
        int lane = (o >> 3) & 63;
        int kbase = ks * 32 + ((lane >> 4) & 3) * 8;
        int n = lane & 15;
        short8 v;
#pragma unroll
        for (int j = 0; j < 8; j++) v[j] = (short)f32_bf16(ld[kbase + j][n]);
        *(short8*)(d + o) = v;
    }
}

// ---------------- fused grouped 2-layer MLP ----------------
// Round-5 change: sched_barrier(0) was a no-op (VGPR stayed 128; IR passes may
// cross an inaccessiblememonly intrinsic). Pin each 16-frag weight-load batch
// with an opaque-USE inline asm: the data dependency forces all 16 loads to
// issue before the pin -> pipelined vmcnt(15..0) instead of serial vmcnt(0).
// bw1 pin sits right before the layer-1 MFMA loop; bw2 pin sits after the
// bias/relu VALU pass so the batch latency hides under it.
#define SLOTS_PER_XCD 288
__global__ __launch_bounds__(256, 2) void k_mlp(
    const float* __restrict__ x, const float* __restrict__ b1, const float* __restrict__ b2,
    const unsigned short* __restrict__ w1fr, const unsigned short* __restrict__ w2fr,
    const int* __restrict__ bucket, const int* __restrict__ offsets,
    const int* __restrict__ tilep, float* __restrict__ out)
{
    __shared__ __align__(16) unsigned short xs[4 * 8 * 64 * 8];  // 32 KB
    __shared__ __align__(16) unsigned short hs[4 * 4 * 64 * 8];  // 16 KB
    __shared__ int rows_s[64];

    int slots = gridDim.x >> 3;
    int xcd  = blockIdx.x & 7;
    int slot = blockIdx.x >> 3;
    int eA = xcd, eB = xcd + 8;
    int T0 = tilep[eA + 1] - tilep[eA];
    int T1 = tilep[eB + 1] - tilep[eB];
    int total = T0 + T1;

    int t = threadIdx.x;
    int lane = t & 63, w = t >> 6;
    int l15 = lane & 15, quad = lane >> 4;

    for (int s = slot; s < total; s += slots) {
        int e    = (s < T0) ? eA : eB;
        int tile = (s < T0) ? s  : s - T0;
        int off  = offsets[e];
        int cnt  = offsets[e + 1] - off;
        int valid = min(64, cnt - tile * 64);

        if (t < 64)
            rows_s[t] = bucket[off + tile * 64 + min(t, valid - 1)];
        __syncthreads();

        // stage x tile f32->bf16 into swizzled A-frag order (nt: read-once stream)
#pragma unroll
        for (int p = 0; p < 8; p++) {
            int item = p * 256 + t;
            int c8 = item & 31, r = item >> 5;
            const float* xr = x + (size_t)rows_s[r] * IN_SZ + c8 * 8;
            floatx4 v0 = __builtin_nontemporal_load((const floatx4*)xr);
            floatx4 v1 = __builtin_nontemporal_load((const floatx4*)(xr + 4));
            int ks = c8 >> 2, q = c8 & 3;
            short8 o;
            o[0] = (short)f32_bf16(v0.x); o[1] = (short)f32_bf16(v0.y);
            o[2] = (short)f32_bf16(v0.z); o[3] = (short)f32_bf16(v0.w);
            o[4] = (short)f32_bf16(v1.x); o[5] = (short)f32_bf16(v1.y);
            o[6] = (short)f32_bf16(v1.z); o[7] = (short)f32_bf16(v1.w);
            *(short8*)&xs[(((r >> 4) * 8 + ks) * 64 + q * 16 + ((r & 15) ^ ks)) * 8] = o;
        }
        __syncthreads();

        floatx4 acc2[4][4] = {};  // [m-tile][n-tile], out cols w*64 + j*16 + l15
        const unsigned short* w1e = w1fr + (size_t)e * 64 * 4096;        // 64 n16 x (8 ks x 512)
        const unsigned short* w2e = w2fr + (size_t)e * 16 * 32 * 512;    // 16 n16 x (32 kst x 512)

        for (int hc = 0; hc < 8; hc++) {
            // ---- layer 1: wave w computes hidden cols hc*128 + w*32 + j1*16 + l15
            int n16_0 = hc * 8 + w * 2;
            const unsigned short* bb0 = w1e + (size_t)n16_0 * 4096 + lane * 8;

            // batch-load all 16 layer-1 weight frags
            short8 bw1[2][8];
#pragma unroll
            for (int ks = 0; ks < 8; ks++) {
                bw1[0][ks] = *(const short8*)(bb0 + ks * 512);
                bw1[1][ks] = *(const short8*)(bb0 + 4096 + ks * 512);
            }
            // opaque USE pin: forces all 16 loads issued before this point,
            // values live in regs -> pipelined waitcnts, stall-free MFMA loop
            asm volatile("" ::
                "v"(bw1[0][0]), "v"(bw1[0][1]), "v"(bw1[0][2]), "v"(bw1[0][3]),
                "v"(bw1[0][4]), "v"(bw1[0][5]), "v"(bw1[0][6]), "v"(bw1[0][7]),
                "v"(bw1[1][0]), "v"(bw1[1][1]), "v"(bw1[1][2]), "v"(bw1[1][3]),
                "v"(bw1[1][4]), "v"(bw1[1][5]), "v"(bw1[1][6]), "v"(bw1[1][7]));

            floatx4 acc1[2][4] = {};
#pragma unroll
            for (int ks = 0; ks < 8; ks++) {
                int xoff = (ks * 64 + quad * 16 + (l15 ^ ks)) * 8;
#pragma unroll
                for (int i = 0; i < 4; i++) {
                    short8 af = *(const short8*)&xs[i * 4096 + xoff];
                    acc1[0][i] = __builtin_amdgcn_mfma_f32_16x16x32_bf16(af, bw1[0][ks], acc1[0][i], 0, 0, 0);
                    acc1[1][i] = __builtin_amdgcn_mfma_f32_16x16x32_bf16(af, bw1[1][ks], acc1[1][i], 0, 0, 0);
                }
            }

            // issue ALL layer-2 weight frags; pin comes AFTER the bias/relu
            // VALU pass so the batch round-trip hides under it
            short8 bw2[4][4];
#pragma unroll
            for (int j = 0; j < 4; j++)
#pragma unroll
                for (int ks2 = 0; ks2 < 4; ks2++)
                    bw2[j][ks2] = *(const short8*)(w2e + (((size_t)(w * 4 + j) * 32) + hc * 4 + ks2) * 512 + lane * 8);

            // bias + relu; C-layout -> hs A-frag order
            int n1base = hc * 128 + w * 32;
#pragma unroll
            for (int j1 = 0; j1 < 2; j1++) {
                float b1v = b1[e * HID + n1base + j1 * 16 + l15];
                int q2 = j1 * 2 + (l15 >> 3);
                int j2 = l15 & 7;
#pragma unroll
                for (int i = 0; i < 4; i++) {
#pragma unroll
                    for (int r = 0; r < 4; r++) {
                        float v = acc1[j1][i][r] + b1v;
                        v = v > 0.f ? v : 0.f;
                        int m15 = quad * 4 + r;
                        hs[((i * 4 + w) * 64 + q2 * 16 + (m15 ^ q2)) * 8 + j2] = f32_bf16(v);
                    }
                }
            }
            asm volatile("" ::
                "v"(bw2[0][0]), "v"(bw2[0][1]), "v"(bw2[0][2]), "v"(bw2[0][3]),
                "v"(bw2[1][0]), "v"(bw2[1][1]), "v"(bw2[1][2]), "v"(bw2[1][3]),
                "v"(bw2[2][0]), "v"(bw2[2][1]), "v"(bw2[2][2]), "v"(bw2[2][3]),
                "v"(bw2[3][0]), "v"(bw2[3][1]), "v"(bw2[3][2]), "v"(bw2[3][3]));
            __syncthreads();
            // ---- layer 2: acc2 += h_chunk @ W2 chunk
#pragma unroll
            for (int ks2 = 0; ks2 < 4; ks2++) {
                int hoff = (ks2 * 64 + quad * 16 + (l15 ^ quad)) * 8;
                short8 af[4];
#pragma unroll
                for (int i = 0; i < 4; i++)
                    af[i] = *(const short8*)&hs[i * 2048 + hoff];
#pragma unroll
                for (int j = 0; j < 4; j++) {
#pragma unroll
                    for (int i = 0; i < 4; i++)
                        acc2[i][j] = __builtin_amdgcn_mfma_f32_16x16x32_bf16(af[i], bw2[j][ks2], acc2[i][j], 0, 0, 0);
                }
            }
            __syncthreads();
        }

        // epilogue: + b2, scatter rows back (nt: write-once stream)
#pragma unroll
        for (int j = 0; j < 4; j++) {
            int col = w * 64 + j * 16 + l15;
            float b2v = b2[e * OUT_SZ + col];
#pragma unroll
            for (int i = 0; i < 4; i++) {
#pragma unroll
                for (int r = 0; r < 4; r++) {
                    int rt = 16 * i + quad * 4 + r;
                    if (rt < valid)
                        __builtin_nontemporal_store(acc2[i][j][r] + b2v,
                                                    &out[(size_t)rows_s[rt] * OUT_SZ + col]);
                }
            }
        }
        // protect rows_s / xs before the next grid-stride iteration overwrites them
        __syncthreads();
    }
}

extern "C" void kernel_launch(void* const* d_in, const int* in_sizes, int n_in,
                              void* d_out, int out_size, void* d_ws, size_t ws_size,
                              hipStream_t stream) {
    const float* x  = (const float*)d_in[0];
    const float* W1 = (const float*)d_in[1];
    const float* b1 = (const float*)d_in[2];
    const float* W2 = (const float*)d_in[3];
    const float* b2 = (const float*)d_in[4];
    const int*  ids = (const int*)d_in[5];
    float* out = (float*)d_out;

    char* ws = (char*)d_ws;
    int* counts  = (int*)(ws);          // 16
    int* cursors = (int*)(ws + 64);     // 16
    int* offsets = (int*)(ws + 128);    // 17
    int* tilep   = (int*)(ws + 256);    // 17
    int* bucket  = (int*)(ws + 1024);   // 131072 ints
    unsigned short* w1fr = (unsigned short*)(ws + (1 << 20));           // 8.39 MB
    unsigned short* w2fr = w1fr + (size_t)NE * HID * IN_SZ;             // 8.39 MB

    (void)hipMemsetAsync(ws, 0, 512, stream);
    hipLaunchKernelGGL(k_hist,    dim3(256), dim3(256), 0, stream, ids, counts);
    hipLaunchKernelGGL(k_scan,    dim3(1),   dim3(1),   0, stream, counts, offsets, tilep);
    hipLaunchKernelGGL(k_scatter, dim3(N_FEATS / SC_CHUNK), dim3(256), 0, stream,
                       ids, offsets, cursors, bucket);
    // W1: [16][256][1024] -> frag order; W2: [16][1024][256] -> frag order
    hipLaunchKernelGGL(k_pack, dim3(IN_SZ / 256, HID / 16, NE), dim3(256), 0, stream,
                       W1, w1fr, IN_SZ, HID);
    hipLaunchKernelGGL(k_pack, dim3(HID / 256, OUT_SZ / 16, NE), dim3(256), 0, stream,
                       W2, w2fr, HID, OUT_SZ);
    hipLaunchKernelGGL(k_mlp, dim3(8 * SLOTS_PER_XCD), dim3(256), 0, stream,
                       x, b1, b2, w1fr, w2fr, bucket, offsets, tilep, out);
}